// Round 1
// baseline (51.663 us; speedup 1.0000x reference)
//
#include <hip/hip_runtime.h>

// out = conv7x7(x, W1eff) + beff   where
//   P     = W2^200                       (9-matmul addition chain)
//   v     = sum_{k=0}^{199} W2^k b2      (vector doubling recursion)
//   W1eff = P @ W1  (over channel dim),  beff = P @ b1 + v
//
// ws layout (floats): [0..4095] P (row-major 64x64)
//                     [4096..4159] beff
//                     [4160..13567] W1eff (64 x 147)

#define S72 72  // LDS row stride for 64x64 matrices (bank-conflict aware, 16B-aligned)

__device__ __forceinline__ void mm64(const float* AT, const float* B,
                                     float* D, float* DT, int r0, int c0)
{
  // D = A*B for 64x64 (stride S72), given A^T and B. Also writes D^T.
  // Thread computes a 4x4 tile at (r0, c0).
  float acc[4][4];
#pragma unroll
  for (int i = 0; i < 4; ++i)
#pragma unroll
    for (int j = 0; j < 4; ++j) acc[i][j] = 0.f;

#pragma unroll 8
  for (int k = 0; k < 64; ++k) {
    const float4 a  = *(const float4*)(AT + k * S72 + r0);
    const float4 bv = *(const float4*)(B  + k * S72 + c0);
    const float av[4] = {a.x, a.y, a.z, a.w};
    const float bb[4] = {bv.x, bv.y, bv.z, bv.w};
#pragma unroll
    for (int i = 0; i < 4; ++i)
#pragma unroll
      for (int j = 0; j < 4; ++j) acc[i][j] += av[i] * bb[j];
  }
#pragma unroll
  for (int i = 0; i < 4; ++i)
    *(float4*)(D + (r0 + i) * S72 + c0) =
        make_float4(acc[i][0], acc[i][1], acc[i][2], acc[i][3]);
#pragma unroll
  for (int j = 0; j < 4; ++j)
    *(float4*)(DT + (c0 + j) * S72 + r0) =
        make_float4(acc[0][j], acc[1][j], acc[2][j], acc[3][j]);
}

// K1: single block. P = W2^200, beff = P b1 + v. Writes P and beff to ws.
__global__ __launch_bounds__(256) void chain_kernel(
    const float* __restrict__ W2g, const float* __restrict__ b2g,
    const float* __restrict__ b1g, float* __restrict__ ws)
{
  __shared__ float Wm[64 * S72];
  __shared__ float buf0[64 * S72], buf0T[64 * S72];
  __shared__ float buf1[64 * S72], buf1T[64 * S72];
  __shared__ float vv[64], tv[64], b2s[64];

  const int t = threadIdx.x;
  for (int i = t; i < 4096; i += 256) {
    const int r = i >> 6, c = i & 63;
    const float w = W2g[i];
    Wm[r * S72 + c]    = w;
    buf0[r * S72 + c]  = w;   // P = W2   (n = 1)
    buf0T[c * S72 + r] = w;   // P^T
  }
  if (t < 64) { const float b = b2g[t]; vv[t] = b; b2s[t] = b; }
  __syncthreads();

  float *P = buf0, *PT = buf0T, *T = buf1, *TT = buf1T;
  const int r0 = (t >> 4) << 2;
  const int c0 = (t & 15) << 2;

  // 200 = 0b11001000 ; after the leading bit: 1,0,0,1,0,0,0
#pragma unroll
  for (int s = 0; s < 7; ++s) {
    // ---- double: v <- v + P v ; P <- P*P ----
    if (t < 64) {
      float a = 0.f;
#pragma unroll 8
      for (int k = 0; k < 64; ++k) a += PT[k * S72 + t] * vv[k];
      tv[t] = vv[t] + a;
    }
    __syncthreads();
    mm64(PT, P, T, TT, r0, c0);
    __syncthreads();
    if (t < 64) vv[t] = tv[t];
    { float* x = P; P = T; T = x; x = PT; PT = TT; TT = x; }
    __syncthreads();

    if (s == 0 || s == 3) {
      // ---- increment: v <- v + P b2 ; P <- P*W2 ----
      if (t < 64) {
        float a = 0.f;
#pragma unroll 8
        for (int k = 0; k < 64; ++k) a += PT[k * S72 + t] * b2s[k];
        tv[t] = vv[t] + a;
      }
      __syncthreads();
      mm64(PT, Wm, T, TT, r0, c0);
      __syncthreads();
      if (t < 64) vv[t] = tv[t];
      { float* x = P; P = T; T = x; x = PT; PT = TT; TT = x; }
      __syncthreads();
    }
  }

  for (int i = t; i < 4096; i += 256)
    ws[i] = P[(i >> 6) * S72 + (i & 63)];
  if (t < 64) {
    float a = 0.f;
#pragma unroll 8
    for (int k = 0; k < 64; ++k) a += PT[k * S72 + t] * b1g[k];
    ws[4096 + t] = a + vv[t];
  }
}

// K2: W1eff[o][j] = sum_c P[o][c] * W1[c][j]   (j over 3*7*7=147)
__global__ __launch_bounds__(192) void w1eff_kernel(
    const float* __restrict__ W1g, float* __restrict__ ws)
{
  const int o = blockIdx.x;
  const int j = threadIdx.x;
  if (j >= 147) return;
  const float* Prow = ws + o * 64;  // wave-uniform -> scalar loads
  float a = 0.f;
#pragma unroll 8
  for (int c = 0; c < 64; ++c) a += Prow[c] * W1g[c * 147 + j];
  ws[4160 + o * 147 + j] = a;
}

// K3: 7x7 VALID conv with W1eff + beff. Grid 512 = 4 b * 64 y * 2 x-halves.
// Block 256: o = t&63, pixel-group = t>>6 (8 consecutive x each).
__global__ __launch_bounds__(256) void conv_kernel(
    const float* __restrict__ xg, const float* __restrict__ ws,
    float* __restrict__ out)
{
  __shared__ float xs[1470];    // [3][7][70]
  __shared__ float Wls[9408];   // [64][147]
  __shared__ float bs[64];

  const int t = threadIdx.x;
  const int bid = blockIdx.x;
  const int b = bid >> 7, y = (bid >> 1) & 63, xh = bid & 1;

  for (int i = t; i < 1470; i += 256) {
    const int c = i / 490, rem = i - c * 490;
    const int ky = rem / 70, col = rem - ky * 70;
    xs[i] = xg[((b * 3 + c) * 70 + (y + ky)) * 70 + col];
  }
  const float4* wg4 = (const float4*)(ws + 4160);
  float4* wl4 = (float4*)Wls;
  for (int i = t; i < 2352; i += 256) wl4[i] = wg4[i];
  if (t < 64) bs[t] = ws[4096 + t];
  __syncthreads();

  const int o = t & 63, pg = t >> 6;
  const int x0 = xh * 32 + pg * 8;

  float acc[8];
  const float bv = bs[o];
#pragma unroll
  for (int j = 0; j < 8; ++j) acc[j] = bv;

  for (int c = 0; c < 3; ++c) {
#pragma unroll
    for (int ky = 0; ky < 7; ++ky) {
      const float* xrow = &xs[(c * 7 + ky) * 70 + x0];
      float xw[14];
#pragma unroll
      for (int u = 0; u < 14; ++u) xw[u] = xrow[u];  // wave-uniform -> LDS broadcast
      const float* wrow = &Wls[o * 147 + c * 49 + ky * 7];
#pragma unroll
      for (int kx = 0; kx < 7; ++kx) {
        const float w = wrow[kx];  // lane stride 147 floats -> 2-way (free)
#pragma unroll
        for (int j = 0; j < 8; ++j) acc[j] += w * xw[kx + j];
      }
    }
  }

  float* op = out + (((b * 64 + o) * 64 + y) * 64) + x0;
  *(float4*)op       = make_float4(acc[0], acc[1], acc[2], acc[3]);
  *(float4*)(op + 4) = make_float4(acc[4], acc[5], acc[6], acc[7]);
}

extern "C" void kernel_launch(void* const* d_in, const int* in_sizes, int n_in,
                              void* d_out, int out_size, void* d_ws, size_t ws_size,
                              hipStream_t stream) {
  const float* x  = (const float*)d_in[0];  // [4,3,70,70]
  const float* W1 = (const float*)d_in[1];  // [64,3,7,7]
  const float* b1 = (const float*)d_in[2];  // [64]
  const float* W2 = (const float*)d_in[3];  // [64,64]
  const float* b2 = (const float*)d_in[4];  // [64]
  float* out = (float*)d_out;               // [4,64,64,64] f32
  float* ws  = (float*)d_ws;                // needs 13568 floats = 54.3 KB

  chain_kernel<<<1, 256, 0, stream>>>(W2, b2, b1, ws);
  w1eff_kernel<<<64, 192, 0, stream>>>(W1, ws);
  conv_kernel<<<512, 256, 0, stream>>>(x, ws, out);
}

// Round 2
// 42.426 us; speedup vs baseline: 1.2177x; 1.2177x over previous
//
#include <hip/hip_runtime.h>

// out = conv7x7(x, W1eff) + beff   where
//   P     = W2^200                       (9-matmul addition chain, split-bf16 MFMA)
//   v     = sum_{k=0}^{199} W2^k b2      (vector doubling recursion, wave-0 regs)
//   W1eff = P @ W1,  beff = P @ b1 + v
//
// ws layout (floats): [0..4095] P (row-major 64x64)
//                     [4096..4159] beff
//                     [4160..13567] W1eff (64 x 147)

typedef __attribute__((ext_vector_type(8))) short bf16x8;
typedef __attribute__((ext_vector_type(4))) short bf16x4;
typedef __attribute__((ext_vector_type(4))) float f32x4;

__device__ __forceinline__ short f2bf(float x) {  // RNE f32 -> bf16
  unsigned u = __float_as_uint(x);
  return (short)((u + 0x7fffu + ((u >> 16) & 1u)) >> 16);
}
__device__ __forceinline__ float bf2f(short h) {
  return __uint_as_float(((unsigned)(unsigned short)h) << 16);
}

// LDS frag load: row r, k-offset k0 (multiple of 8). XOR-swizzle (T2) so the
// 128B row stride doesn't put all 16 rows of a frag-read in one bank group.
__device__ __forceinline__ bf16x8 ldfrag(const short* buf, int r, int k0) {
  int s = (r * 64 + k0) ^ ((r & 7) << 3);
  return *(const bf16x8*)(buf + s);
}

template <bool USEW2>
__device__ __forceinline__ void do_mul(
    const short* ah_, const short* al_, const short* bth, const short* btl,
    bf16x8 w2h0, bf16x8 w2h1, bf16x8 w2l0, bf16x8 w2l1,
    short* dh, short* dl, short* dth, short* dtl,
    int tr, int tc, int frow, int fkb)
{
  f32x4 acc = {0.f, 0.f, 0.f, 0.f};
#pragma unroll
  for (int s = 0; s < 2; ++s) {
    const int k0 = 32 * s + 8 * fkb;
    bf16x8 Ah = ldfrag(ah_, 16 * tr + frow, k0);
    bf16x8 Al = ldfrag(al_, 16 * tr + frow, k0);
    bf16x8 Bh = USEW2 ? (s == 0 ? w2h0 : w2h1) : ldfrag(bth, 16 * tc + frow, k0);
    bf16x8 Bl = USEW2 ? (s == 0 ? w2l0 : w2l1) : ldfrag(btl, 16 * tc + frow, k0);
    acc = __builtin_amdgcn_mfma_f32_16x16x32_bf16(Ah, Bh, acc, 0, 0, 0);
    acc = __builtin_amdgcn_mfma_f32_16x16x32_bf16(Ah, Bl, acc, 0, 0, 0);
    acc = __builtin_amdgcn_mfma_f32_16x16x32_bf16(Al, Bh, acc, 0, 0, 0);
  }
  // C/D layout: col = lane&15, row = 4*(lane>>4)+j  (m89-verified)
  const int ocol = 16 * tc + frow;
  const int orow0 = 16 * tr + fkb * 4;
  bf16x4 h4, l4;
#pragma unroll
  for (int j = 0; j < 4; ++j) {
    const float x = acc[j];
    const short h = f2bf(x);
    const short l = f2bf(x - bf2f(h));
    const int r = orow0 + j;
    dh[(r * 64 + ocol) ^ ((r & 7) << 3)] = h;
    dl[(r * 64 + ocol) ^ ((r & 7) << 3)] = l;
    h4[j] = h; l4[j] = l;
  }
  const int si = (ocol * 64 + orow0) ^ ((ocol & 7) << 3);
  *(bf16x4*)(dth + si) = h4;
  *(bf16x4*)(dtl + si) = l4;
}

// v' = vin + (P u)[lane], P read as hi+lo from its transposed LDS buffer.
__device__ __forceinline__ float vupd(const short* pth, const short* ptl,
                                      float u, float vin, int lane) {
  float a = 0.f;
#pragma unroll 8
  for (int k = 0; k < 64; ++k) {
    const int si = (k * 64 + lane) ^ ((k & 7) << 3);
    a += (bf2f(pth[si]) + bf2f(ptl[si])) * __shfl(u, k, 64);
  }
  return vin + a;
}

__global__ __launch_bounds__(1024) void chain_kernel(
    const float* __restrict__ W2g, const float* __restrict__ b2g,
    const float* __restrict__ b1g, float* __restrict__ ws)
{
  __shared__ __align__(16) short B0h[4096], B0l[4096], B0Th[4096], B0Tl[4096];
  __shared__ __align__(16) short B1h[4096], B1l[4096], B1Th[4096], B1Tl[4096];
  // exactly 64 KB

  const int t = threadIdx.x;
  const int wid = t >> 6, lane = t & 63;
  const int tr = wid >> 2, tc = wid & 3;
  const int frow = lane & 15, fkb = lane >> 4;

  // init P = W2 (split hi/lo, row-major + transposed)
  for (int i = t; i < 4096; i += 1024) {
    const int r = i >> 6, c = i & 63;
    const float w = W2g[i];
    const short h = f2bf(w);
    const short l = f2bf(w - bf2f(h));
    B0h[(r * 64 + c) ^ ((r & 7) << 3)] = h;
    B0l[(r * 64 + c) ^ ((r & 7) << 3)] = l;
    B0Th[(c * 64 + r) ^ ((c & 7) << 3)] = h;
    B0Tl[(c * 64 + r) ^ ((c & 7) << 3)] = l;
  }

  // per-wave W2 B-fragments in registers (for the two P<-P*W2 steps):
  // B[k][c], c = 16*tc + frow, k = 32*s + 8*fkb + j
  bf16x8 w2h0, w2h1, w2l0, w2l1;
#pragma unroll
  for (int j = 0; j < 8; ++j) {
    {
      const float w = W2g[(8 * fkb + j) * 64 + 16 * tc + frow];
      const short h = f2bf(w);
      w2h0[j] = h; w2l0[j] = f2bf(w - bf2f(h));
    }
    {
      const float w = W2g[(32 + 8 * fkb + j) * 64 + 16 * tc + frow];
      const short h = f2bf(w);
      w2h1[j] = h; w2l1[j] = f2bf(w - bf2f(h));
    }
  }

  float vc = 0.f, b2r = 0.f;
  if (wid == 0) { b2r = b2g[lane]; vc = b2r; }

  short *ph = B0h, *pl = B0l, *pth = B0Th, *ptl = B0Tl;
  short *dh = B1h, *dl = B1l, *dth = B1Th, *dtl = B1Tl;

  // 200 = 0b11001000: after leading bit the increment steps are s7==0 and s7==3
#pragma unroll
  for (int s7 = 0; s7 < 7; ++s7) {
    __syncthreads();
    if (wid == 0) vc = vupd(pth, ptl, vc, vc, lane);          // v <- v + P v
    do_mul<false>(ph, pl, pth, ptl, w2h0, w2h1, w2l0, w2l1,
                  dh, dl, dth, dtl, tr, tc, frow, fkb);       // T <- P*P
    { short* x; x=ph; ph=dh; dh=x; x=pl; pl=dl; dl=x;
      x=pth; pth=dth; dth=x; x=ptl; ptl=dtl; dtl=x; }
    if (s7 == 0 || s7 == 3) {
      __syncthreads();
      if (wid == 0) vc = vupd(pth, ptl, b2r, vc, lane);       // v <- v + P b2
      do_mul<true>(ph, pl, nullptr, nullptr, w2h0, w2h1, w2l0, w2l1,
                   dh, dl, dth, dtl, tr, tc, frow, fkb);      // T <- P*W2
      { short* x; x=ph; ph=dh; dh=x; x=pl; pl=dl; dl=x;
        x=pth; pth=dth; dth=x; x=ptl; ptl=dtl; dtl=x; }
    }
  }
  __syncthreads();

  for (int i = t; i < 4096; i += 1024) {
    const int r = i >> 6, c = i & 63;
    const int si = (r * 64 + c) ^ ((r & 7) << 3);
    ws[i] = bf2f(ph[si]) + bf2f(pl[si]);
  }
  if (wid == 0) {
    const float b1r = b1g[lane];
    ws[4096 + lane] = vupd(pth, ptl, b1r, vc, lane);          // beff = P b1 + v
  }
}

// K2: W1eff[o][j] = sum_c P[o][c] * W1[c][j]   (j over 3*7*7=147)
__global__ __launch_bounds__(192) void w1eff_kernel(
    const float* __restrict__ W1g, float* __restrict__ ws)
{
  const int o = blockIdx.x;
  const int j = threadIdx.x;
  if (j >= 147) return;
  const float* Prow = ws + o * 64;  // wave-uniform -> scalar loads
  float a = 0.f;
#pragma unroll 8
  for (int c = 0; c < 64; ++c) a += Prow[c] * W1g[c * 147 + j];
  ws[4160 + o * 147 + j] = a;
}

// K3: 7x7 VALID conv with W1eff + beff. Grid 512 = 4 b * 64 y * 2 x-halves.
__global__ __launch_bounds__(256) void conv_kernel(
    const float* __restrict__ xg, const float* __restrict__ ws,
    float* __restrict__ out)
{
  __shared__ float xs[1470];    // [3][7][70]
  __shared__ float Wls[9408];   // [64][147]
  __shared__ float bs[64];

  const int t = threadIdx.x;
  const int bid = blockIdx.x;
  const int b = bid >> 7, y = (bid >> 1) & 63, xh = bid & 1;

  for (int i = t; i < 1470; i += 256) {
    const int c = i / 490, rem = i - c * 490;
    const int ky = rem / 70, col = rem - ky * 70;
    xs[i] = xg[((b * 3 + c) * 70 + (y + ky)) * 70 + col];
  }
  const float4* wg4 = (const float4*)(ws + 4160);
  float4* wl4 = (float4*)Wls;
  for (int i = t; i < 2352; i += 256) wl4[i] = wg4[i];
  if (t < 64) bs[t] = ws[4096 + t];
  __syncthreads();

  const int o = t & 63, pg = t >> 6;
  const int x0 = xh * 32 + pg * 8;

  float acc[8];
  const float bv = bs[o];
#pragma unroll
  for (int j = 0; j < 8; ++j) acc[j] = bv;

  for (int c = 0; c < 3; ++c) {
#pragma unroll
    for (int ky = 0; ky < 7; ++ky) {
      const float* xrow = &xs[(c * 7 + ky) * 70 + x0];
      float xw[14];
#pragma unroll
      for (int u = 0; u < 14; ++u) xw[u] = xrow[u];
      const float* wrow = &Wls[o * 147 + c * 49 + ky * 7];
#pragma unroll
      for (int kx = 0; kx < 7; ++kx) {
        const float w = wrow[kx];
#pragma unroll
        for (int j = 0; j < 8; ++j) acc[j] += w * xw[kx + j];
      }
    }
  }

  float* op = out + (((b * 64 + o) * 64 + y) * 64) + x0;
  *(float4*)op       = make_float4(acc[0], acc[1], acc[2], acc[3]);
  *(float4*)(op + 4) = make_float4(acc[4], acc[5], acc[6], acc[7]);
}

extern "C" void kernel_launch(void* const* d_in, const int* in_sizes, int n_in,
                              void* d_out, int out_size, void* d_ws, size_t ws_size,
                              hipStream_t stream) {
  const float* x  = (const float*)d_in[0];  // [4,3,70,70]
  const float* W1 = (const float*)d_in[1];  // [64,3,7,7]
  const float* b1 = (const float*)d_in[2];  // [64]
  const float* W2 = (const float*)d_in[3];  // [64,64]
  const float* b2 = (const float*)d_in[4];  // [64]
  float* out = (float*)d_out;               // [4,64,64,64] f32
  float* ws  = (float*)d_ws;                // 13568 floats

  chain_kernel<<<1, 1024, 0, stream>>>(W2, b2, b1, ws);
  w1eff_kernel<<<64, 192, 0, stream>>>(W1, ws);
  conv_kernel<<<512, 256, 0, stream>>>(x, ws, out);
}